// Round 8
// baseline (197.620 us; speedup 1.0000x reference)
//
#include <hip/hip_runtime.h>
#include <stdint.h>

// GCN: out[u] = (sum_{(u,v) in E} x[v]) @ W + bias, E sorted by u.
// R7 post-mortem: VGPR_Count=56 — the allocator serialized the "8 loads in
// flight" block into load->wait->fma chains; per-wave critical path ~24k cyc,
// and adding waves (R5->R7) didn't help => intra-wave MLP is the lever.
// R8: __launch_bounds__(256,2) frees ~256 VGPRs; 32-edge volley (16 float4
// loads, ONE wait) covers a whole avg-degree row per round-trip; dead slots
// are exec-masked (no junk traffic) instead of scale-by-zero.

typedef __attribute__((ext_vector_type(8))) short bf16x8;   // 8 bf16 = 4 VGPRs
typedef __attribute__((ext_vector_type(4))) float f32x4;    // MFMA C/D

#define WSTRIDE 136   // A-tile k-stride (bf16 elems), multiple of 8 for 16B reads

__device__ __forceinline__ unsigned short f2bf(float f) {
    union { float f; uint32_t u; } c; c.f = f;
    uint32_t u = c.u;
    uint32_t r = (u + 0x7FFFu + ((u >> 16) & 1u)) >> 16;  // RNE
    return (unsigned short)r;
}

__global__ __launch_bounds__(256)
void gcn_setup(const int* __restrict__ eu, const float* __restrict__ W,
               int* __restrict__ row_ptr, unsigned short* __restrict__ Wg,
               int N, int E)
{
    const int g = blockIdx.x * 256 + threadIdx.x;
    if (g < E) {                       // interior transitions (bounded gaps)
        int cur  = eu[g];
        int prev = (g > 0) ? eu[g - 1] : -1;
        for (int r = prev + 1; r <= cur; ++r) row_ptr[r] = g;
    }
    if (g <= N) {                      // parallel tail fill
        int last = eu[E - 1];
        if (g > last) row_ptr[g] = E;
    }
    if (g < 16384) {                   // W^T bf16
        int k = g >> 7, n = g & 127;
        Wg[n * 128 + k] = f2bf(W[g]);
    }
}

__global__ __launch_bounds__(256, 2)   // 2 waves/EU min -> ~256 VGPR budget
void gcn_main(const float* __restrict__ x,
              const int* __restrict__ ev,        // src ids, int32
              const int* __restrict__ row_ptr,   // [N+1]
              const unsigned short* __restrict__ Wg,  // bf16 W^T [128][128]
              const float* __restrict__ bias,
              float* __restrict__ out,           // [N][128] f32
              int N, int E, int TW)              // TW = grid*4 (total waves)
{
    __shared__ __align__(16) unsigned short At[2][16 * WSTRIDE]; // per wave-pair

    const int t    = threadIdx.x;
    const int wid  = t >> 6;
    const int lane = t & 63;
    const int quad = lane >> 4;
    const int l15  = lane & 15;
    const int half = lane >> 5;   // 0/1: which edge of a pair
    const int l31  = lane & 31;   // float4 slot within a 128-f row

    const int wg = blockIdx.x * 4 + wid;   // global wave id; rows = wg + m*TW

    // ---- Row boundaries: lanes 0-7 starts, lanes 8-15 ends ----
    int bnd;
    {
        const int m8 = lane & 7;
        const int e8 = (lane >> 3) & 1;
        bnd = row_ptr[min(wg + m8 * TW + e8, N)];
    }

    unsigned short* Am = &At[wid >> 1][(wid & 1) * 8 * WSTRIDE];
    const float4* x4 = (const float4*)x;
    const float4 fz = {0.f, 0.f, 0.f, 0.f};

    // prefetch row 0's first 64 edge indices
    int vIdx = ev[min(__shfl(bnd, 0) + lane, E - 1)];

    for (int m = 0; m < 8; ++m) {
        const int s = __shfl(bnd, m);
        const int c = __shfl(bnd, m + 8) - s;
        // prefetch next row's indices BEFORE this row's gather-wait
        int vNext = (m < 7) ? ev[min(__shfl(bnd, m + 1) + lane, E - 1)] : 0;

        float4 a0 = fz, a1 = fz, a2 = fz, a3 = fz;
        for (int base = 0; base < c; base += 32) {
            if (base && ((base & 63) == 0))        // deg > 64: essentially never
                vIdx = ev[min(s + base + lane, E - 1)];
            float4 tv[16];
            #pragma unroll
            for (int k = 0; k < 16; ++k) {         // 16 masked loads, no wait between
                const int eidx = base + 2 * k + half;
                const int v = __shfl(vIdx, eidx & 63);
                tv[k] = (eidx < c) ? x4[((long long)v << 5) + l31] : fz;
            }
            #pragma unroll
            for (int k = 0; k < 16; ++k) {         // one wait region, then adds
                float4& a = (k & 3) == 0 ? a0 : (k & 3) == 1 ? a1 : (k & 3) == 2 ? a2 : a3;
                a.x += tv[k].x; a.y += tv[k].y; a.z += tv[k].z; a.w += tv[k].w;
            }
        }
        vIdx = vNext;

        // combine 4 accumulators, then the two wave halves
        a0.x = (a0.x + a1.x) + (a2.x + a3.x);
        a0.y = (a0.y + a1.y) + (a2.y + a3.y);
        a0.z = (a0.z + a1.z) + (a2.z + a3.z);
        a0.w = (a0.w + a1.w) + (a2.w + a3.w);
        a0.x += __shfl_xor(a0.x, 32);
        a0.y += __shfl_xor(a0.y, 32);
        a0.z += __shfl_xor(a0.z, 32);
        a0.w += __shfl_xor(a0.w, 32);
        if (half == 0) {   // lane l31 owns features 4*l31 .. 4*l31+3
            ushort4 pk;
            pk.x = f2bf(a0.x); pk.y = f2bf(a0.y);
            pk.z = f2bf(a0.z); pk.w = f2bf(a0.w);
            *(ushort4*)(Am + m * WSTRIDE + 4 * l31) = pk;   // 8B aligned
        }
    }
    __syncthreads();   // wave-pair shares its 16-row tile

    // ---- MFMA: pair p's 16 logical rows x 64 cols per wave ----
    const int p  = wid >> 1;
    const int ch = wid & 1;
    const unsigned short* Ar = &At[p][0];
    f32x4 acc[4];
    #pragma unroll
    for (int nt = 0; nt < 4; ++nt) { acc[nt].x = 0.f; acc[nt].y = 0.f; acc[nt].z = 0.f; acc[nt].w = 0.f; }

    #pragma unroll
    for (int ks = 0; ks < 4; ++ks) {
        const int kofs = ks * 32 + quad * 8;
        bf16x8 a = *(const bf16x8*)(Ar + l15 * WSTRIDE + kofs);       // A[mi=l15][k..]
        #pragma unroll
        for (int nt = 0; nt < 4; ++nt) {
            const int col = ch * 64 + nt * 16 + l15;
            bf16x8 b = *(const bf16x8*)(Wg + col * 128 + kofs);       // B^T[n=col][k..]
            acc[nt] = __builtin_amdgcn_mfma_f32_16x16x32_bf16(a, b, acc[nt], 0, 0, 0);
        }
    }

    // ---- Epilogue. C/D: col = lane&15, mi = quad*4 + reg.
    // tile row mi -> physical: row = (block*4 + 2p + (mi>>3)) + (mi&7)*TW ----
    const int wgpair = blockIdx.x * 4 + 2 * p;
    #pragma unroll
    for (int nt = 0; nt < 4; ++nt) {
        const int col = ch * 64 + nt * 16 + l15;
        const float bcol = bias[col];
        #pragma unroll
        for (int r = 0; r < 4; ++r) {
            const int mi  = quad * 4 + r;
            const int row = wgpair + (mi >> 3) + (mi & 7) * TW;
            if (row < N)
                __builtin_nontemporal_store(acc[nt][r] + bcol,
                                            &out[(long long)row * 128 + col]);
        }
    }
}

extern "C" void kernel_launch(void* const* d_in, const int* in_sizes, int n_in,
                              void* d_out, int out_size, void* d_ws, size_t ws_size,
                              hipStream_t stream) {
    const float* x    = (const float*)d_in[0];
    const int*   ei   = (const int*)d_in[1];     // int32 on device
    const float* W    = (const float*)d_in[2];
    const float* bias = (const float*)d_in[3];
    float*       out  = (float*)d_out;

    const int N = in_sizes[0] / 128;
    const int E = in_sizes[1] / 2;

    int*            row_ptr = (int*)d_ws;                                  // (N+1)*4 B
    unsigned short* Wg      = (unsigned short*)((char*)d_ws + (((size_t)(N + 1) * 4 + 255) & ~(size_t)255)); // 32 KB

    const int setup_threads = (E > N + 1 ? E : N + 1);
    gcn_setup<<<(setup_threads + 255) / 256, 256, 0, stream>>>(ei, W, row_ptr, Wg, N, E);

    const int grid = (N + 31) / 32;   // 32 logical rows/block, 8 per wave
    const int TW   = grid * 4;
    gcn_main<<<grid, 256, 0, stream>>>(x, ei + E, row_ptr, Wg, bias, out, N, E, TW);
}

// Round 9
// 124.772 us; speedup vs baseline: 1.5838x; 1.5838x over previous
//
#include <hip/hip_runtime.h>
#include <stdint.h>

// GCN: out[u] = (sum_{(u,v) in E} x[v]) @ W + bias, E sorted by u.
// R8 lesson: conditional (ternary) loads serialize; unconditional + scale-by-0
// schedules. R5-R8 floor ~60us is gather latency x concurrency on 327 MB of
// fp32 row traffic. R9: pre-cast x to bf16 (halves bytes + miss lines), gather
// 4 edges/instruction (16 lanes x 16B per edge row) -> 8-slot volley = 32
// edges = one avg-degree row per round trip; 4 rows/wave (grid 2x).
// Fallback to fp32 gather if ws_size can't hold xb (12.8 MB).

typedef __attribute__((ext_vector_type(8))) short bf16x8;   // 8 bf16 = 4 VGPRs
typedef __attribute__((ext_vector_type(4))) float f32x4;    // MFMA C/D

#define WSTRIDE 136   // A-tile k-stride (bf16 elems); 272 B rows (16B-multiple)

__device__ __forceinline__ unsigned short f2bf(float f) {
    union { float f; uint32_t u; } c; c.f = f;
    uint32_t u = c.u;
    uint32_t r = (u + 0x7FFFu + ((u >> 16) & 1u)) >> 16;  // RNE
    return (unsigned short)r;
}
__device__ __forceinline__ float bf2f(unsigned short u) {
    union { uint32_t u; float f; } c; c.u = ((uint32_t)u) << 16;
    return c.f;
}

__global__ __launch_bounds__(256)
void gcn_setup(const int* __restrict__ eu, const float* __restrict__ W,
               int* __restrict__ row_ptr, unsigned short* __restrict__ Wg,
               int N, int E)
{
    const int g = blockIdx.x * 256 + threadIdx.x;
    if (g < E) {                       // interior transitions (bounded gaps)
        int cur  = eu[g];
        int prev = (g > 0) ? eu[g - 1] : -1;
        for (int r = prev + 1; r <= cur; ++r) row_ptr[r] = g;
    }
    if (g <= N) {                      // parallel tail fill (R6's 526us bug fix)
        int last = eu[E - 1];
        if (g > last) row_ptr[g] = E;
    }
    if (g < 16384) {                   // W^T bf16: Wg[n*128+k] = bf16(W[k][n])
        int k = g >> 7, n = g & 127;
        Wg[n * 128 + k] = f2bf(W[g]);
    }
}

__global__ __launch_bounds__(256)
void gcn_cast(const float* __restrict__ x, unsigned short* __restrict__ xb, int n8)
{
    const int g = blockIdx.x * 256 + threadIdx.x;
    if (g < n8) {
        const float4* x4 = (const float4*)x;
        float4 a = x4[2 * g], b = x4[2 * g + 1];
        union { unsigned short u[8]; uint4 v; } pk;
        pk.u[0] = f2bf(a.x); pk.u[1] = f2bf(a.y); pk.u[2] = f2bf(a.z); pk.u[3] = f2bf(a.w);
        pk.u[4] = f2bf(b.x); pk.u[5] = f2bf(b.y); pk.u[6] = f2bf(b.z); pk.u[7] = f2bf(b.w);
        ((uint4*)xb)[g] = pk.v;
    }
}

template<bool BF>
__global__ __launch_bounds__(256)
void gcn_main(const float* __restrict__ x,
              const unsigned short* __restrict__ xb,  // bf16 x (BF path)
              const int* __restrict__ ev,
              const int* __restrict__ row_ptr,        // [N+1]
              const unsigned short* __restrict__ Wg,  // bf16 W^T [128][128]
              const float* __restrict__ bias,
              float* __restrict__ out,                // [N][128] f32
              int N, int E, int TW)                   // TW = grid*4
{
    __shared__ __align__(16) unsigned short At[16 * WSTRIDE];  // block tile [mi][k]

    const int t    = threadIdx.x;
    const int wid  = t >> 6;
    const int lane = t & 63;
    const int quad = lane >> 4;
    const int l15  = lane & 15;

    const int wg = blockIdx.x * 4 + wid;   // wave's rows: wg + m*TW, m=0..3

    // Row bounds: lane 2m -> start of row m, lane 2m+1 -> its end (CSR).
    int bnd;
    {
        const int m = (lane >> 1) & 3, e = lane & 1;
        bnd = row_ptr[min(wg + m * TW + e, N)];
    }

    unsigned short* Am = At + (wid * 4) * WSTRIDE;

    // prefetch row 0's first 64 edge indices
    int vIdx = ev[min(__shfl(bnd, 0) + lane, E - 1)];

    for (int m = 0; m < 4; ++m) {
        const int s = __shfl(bnd, 2 * m);
        const int c = __shfl(bnd, 2 * m + 1) - s;
        // prefetch next row's indices BEFORE this row's gather-wait
        int vNext = (m < 3) ? ev[min(__shfl(bnd, 2 * m + 2) + lane, E - 1)] : 0;

        if constexpr (BF) {
            // 4 edges/instruction: eslot = lane>>4, lane l15 holds feats 8*l15..+7
            const int eslot = lane >> 4;
            const int fo = l15 * 8;
            float fa[8];
            #pragma unroll
            for (int i = 0; i < 8; ++i) fa[i] = 0.f;

            for (int base = 0; base < c; base += 32) {            // 32 edges/volley
                if (base && ((base & 63) == 0))
                    vIdx = ev[min(s + base + lane, E - 1)];
                bf16x8 tv[8];
                float  sc[8];
                #pragma unroll
                for (int k = 0; k < 8; ++k) {                     // unconditional loads
                    const int eidx = base + k * 4 + eslot;
                    int v = __shfl(vIdx, eidx & 63);
                    const bool act = (eidx < c);
                    sc[k] = act ? 1.0f : 0.0f;
                    v = act ? v : 0;                              // dead -> hot row 0
                    tv[k] = *(const bf16x8*)(xb + (size_t)v * 128 + fo);
                }
                #pragma unroll
                for (int k = 0; k < 8; ++k)
                    #pragma unroll
                    for (int i = 0; i < 8; ++i)
                        fa[i] = fmaf(bf2f((unsigned short)tv[k][i]), sc[k], fa[i]);
            }
            #pragma unroll
            for (int i = 0; i < 8; ++i) {                          // reduce 4 eslots
                fa[i] += __shfl_xor(fa[i], 16);
                fa[i] += __shfl_xor(fa[i], 32);
            }
            if (eslot == 0) {
                union { unsigned short u[8]; uint4 v; } pk;
                #pragma unroll
                for (int i = 0; i < 8; ++i) pk.u[i] = f2bf(fa[i]);
                *(uint4*)(Am + m * WSTRIDE + fo) = pk.v;           // 16B aligned
            }
        } else {
            // fp32 fallback: 2 edges/instruction (R7 structure)
            const int half = lane >> 5;
            const int l31  = lane & 31;
            const float4* x4 = (const float4*)x;
            const float4 fz = {0.f, 0.f, 0.f, 0.f};
            float4 a0 = fz, a1 = fz;
            for (int base = 0; base < c; base += 16) {
                if (base && ((base & 63) == 0))
                    vIdx = ev[min(s + base + lane, E - 1)];
                float4 tv[8];
                float  sc[8];
                #pragma unroll
                for (int k = 0; k < 8; ++k) {
                    const int eidx = base + 2 * k + half;
                    int v = __shfl(vIdx, eidx & 63);
                    const bool act = (eidx < c);
                    sc[k] = act ? 1.0f : 0.0f;
                    v = act ? v : 0;
                    tv[k] = x4[((long long)v << 5) + l31];
                }
                #pragma unroll
                for (int k = 0; k < 8; ++k) {
                    float4& a = (k & 1) ? a1 : a0;
                    a.x = fmaf(tv[k].x, sc[k], a.x);
                    a.y = fmaf(tv[k].y, sc[k], a.y);
                    a.z = fmaf(tv[k].z, sc[k], a.z);
                    a.w = fmaf(tv[k].w, sc[k], a.w);
                }
            }
            a0.x += a1.x; a0.y += a1.y; a0.z += a1.z; a0.w += a1.w;
            a0.x += __shfl_xor(a0.x, 32);
            a0.y += __shfl_xor(a0.y, 32);
            a0.z += __shfl_xor(a0.z, 32);
            a0.w += __shfl_xor(a0.w, 32);
            if (half == 0) {
                ushort4 pk;
                pk.x = f2bf(a0.x); pk.y = f2bf(a0.y);
                pk.z = f2bf(a0.z); pk.w = f2bf(a0.w);
                *(ushort4*)(Am + m * WSTRIDE + 4 * l31) = pk;
            }
        }
        vIdx = vNext;
    }
    __syncthreads();   // block shares the 16-row tile

    // ---- MFMA: 16 logical rows x 32 cols per wave ----
    f32x4 acc[2];
    #pragma unroll
    for (int nt = 0; nt < 2; ++nt) { acc[nt].x = 0.f; acc[nt].y = 0.f; acc[nt].z = 0.f; acc[nt].w = 0.f; }

    #pragma unroll
    for (int ks = 0; ks < 4; ++ks) {
        const int kofs = ks * 32 + quad * 8;
        bf16x8 a = *(const bf16x8*)(At + l15 * WSTRIDE + kofs);   // A[mi=l15][k..]
        #pragma unroll
        for (int nt = 0; nt < 2; ++nt) {
            const int col = wid * 32 + nt * 16 + l15;
            bf16x8 b = *(const bf16x8*)(Wg + col * 128 + kofs);   // B^T[n=col][k..]
            acc[nt] = __builtin_amdgcn_mfma_f32_16x16x32_bf16(a, b, acc[nt], 0, 0, 0);
        }
    }

    // ---- Epilogue. C/D: col = lane&15, mi = quad*4 + reg.
    // mi -> physical row: (block*4 + (mi>>2)) + (mi&3)*TW ----
    const int b4 = blockIdx.x * 4;
    #pragma unroll
    for (int nt = 0; nt < 2; ++nt) {
        const int col = wid * 32 + nt * 16 + l15;
        const float bcol = bias[col];
        #pragma unroll
        for (int r = 0; r < 4; ++r) {
            const int mi  = quad * 4 + r;
            const int row = b4 + (mi >> 2) + (mi & 3) * TW;
            if (row < N)
                __builtin_nontemporal_store(acc[nt][r] + bcol,
                                            &out[(long long)row * 128 + col]);
        }
    }
}

extern "C" void kernel_launch(void* const* d_in, const int* in_sizes, int n_in,
                              void* d_out, int out_size, void* d_ws, size_t ws_size,
                              hipStream_t stream) {
    const float* x    = (const float*)d_in[0];
    const int*   ei   = (const int*)d_in[1];     // int32 on device
    const float* W    = (const float*)d_in[2];
    const float* bias = (const float*)d_in[3];
    float*       out  = (float*)d_out;

    const int N = in_sizes[0] / 128;
    const int E = in_sizes[1] / 2;

    const size_t rp_b   = ((size_t)(N + 1) * 4 + 255) & ~(size_t)255;
    const size_t wg_off = rp_b;
    const size_t xb_off = (wg_off + 32768 + 255) & ~(size_t)255;
    const size_t xb_b   = (size_t)N * 128 * 2;

    int*            row_ptr = (int*)d_ws;
    unsigned short* Wg      = (unsigned short*)((char*)d_ws + wg_off);
    unsigned short* xb      = (unsigned short*)((char*)d_ws + xb_off);
    const bool use_bf = (ws_size >= xb_off + xb_b);   // stable across calls

    const int setup_threads = (E > N + 1 ? E : N + 1);
    gcn_setup<<<(setup_threads + 255) / 256, 256, 0, stream>>>(ei, W, row_ptr, Wg, N, E);

    const int grid = (N + 15) / 16;   // 16 logical rows/block, 4 per wave
    const int TW   = grid * 4;
    if (use_bf) {
        const int n8 = N * 16;        // groups of 8 floats
        gcn_cast<<<(n8 + 255) / 256, 256, 0, stream>>>(x, xb, n8);
        gcn_main<true><<<grid, 256, 0, stream>>>(x, xb, ei + E, row_ptr, Wg, bias, out, N, E, TW);
    } else {
        gcn_main<false><<<grid, 256, 0, stream>>>(x, xb, ei + E, row_ptr, Wg, bias, out, N, E, TW);
    }
}